// Round 1
// baseline (181.291 us; speedup 1.0000x reference)
//
#include <hip/hip_runtime.h>
#include <hip/hip_bf16.h>

// Residual conv: out[b,co,h,w] = in[b,co,h,w] + sum_{ci,kh,kw} in[b,ci,h+kh-1,w+kw-1] * W[b,co,ci,kh,kw]
// B=16, C=128, H=W=64, K=3, pad=1. fp32 in/out.
// Strategy: implicit GEMM on mfma_f32_16x16x32_bf16 with 3-term bf16 split precision
// (x = xh + xl, w = wh + wl; acc += xh*wh + xh*wl + xl*wh; error ~1e-5).

typedef __bf16 bf16x8 __attribute__((ext_vector_type(8)));
typedef float f32x4 __attribute__((ext_vector_type(4)));
typedef unsigned short us8 __attribute__((ext_vector_type(8)));
typedef unsigned int uint32_t_;

#define MFMA16 __builtin_amdgcn_mfma_f32_16x16x32_bf16

__device__ __forceinline__ unsigned short f2bf(float f) {
    unsigned int u = __builtin_bit_cast(unsigned int, f);
    u += 0x7fffu + ((u >> 16) & 1u);   // RNE
    return (unsigned short)(u >> 16);
}
__device__ __forceinline__ float bf2f(unsigned short h) {
    return __builtin_bit_cast(float, ((unsigned int)h) << 16);
}

// ---------------- pre-pass: W[b][co][ci][kh][kw] fp32 -> Whi/Wlo[b][p][co][ci] bf16 ----------------
__global__ void w_prepass(const float* __restrict__ W,
                          unsigned short* __restrict__ whi,
                          unsigned short* __restrict__ wlo) {
    int tid = blockIdx.x * 256 + threadIdx.x;     // 0 .. 294911
    int ci8 = (tid & 15) * 8;
    int row = tid >> 4;            // (b*9+p)*128 + co
    int co  = row & 127;
    int bp  = row >> 7;            // b*9 + p
    int p   = bp % 9;
    int b   = bp / 9;
    const float* src = W + ((size_t)(b * 128 + co) * 128 + ci8) * 9 + p;
    us8 ph, pl;
#pragma unroll
    for (int j = 0; j < 8; ++j) {
        float v = src[(size_t)j * 9];
        unsigned short hb = f2bf(v);
        ph[j] = hb;
        pl[j] = f2bf(v - bf2f(hb));
    }
    size_t o = (size_t)row * 128 + ci8;
    *(us8*)&whi[o] = ph;
    *(us8*)&wlo[o] = pl;
}

// ---------------- main conv kernel ----------------
// grid: 1024 blocks (16 batches * 64 rows), 256 threads (4 waves).
// Block: batch b, output row h, all 128 co, 64 px.
// Wave w: co in [w*32, w*32+32) (2 M-tiles), px 0..63 (4 N-tiles).
// LDS: W tile [128 co][3 kw * 32 ci] bf16 hi/lo (row stride 104 shorts),
//      X tile [66 x'][32 ci] bf16 hi/lo transposed halo (row stride 40), x' = x+1.

#define WLD 104
#define XLD 40

template <bool PRE>
__global__ __launch_bounds__(256, 2) void conv_main(
    const float* __restrict__ X, const float* __restrict__ Wg,
    const unsigned short* __restrict__ whi, const unsigned short* __restrict__ wlo,
    float* __restrict__ out) {
    __shared__ unsigned short sWhi[128 * WLD];
    __shared__ unsigned short sWlo[128 * WLD];
    __shared__ unsigned short sXhi[66 * XLD];
    __shared__ unsigned short sXlo[66 * XLD];

    const int tid = threadIdx.x;
    const int lane = tid & 63;
    const int wv = tid >> 6;       // wave 0..3
    const int l15 = lane & 15;
    const int lg = lane >> 4;      // 0..3

    // XCD-aware swizzle (1024 % 8 == 0 -> bijective)
    int blk = blockIdx.x;
    int swz = (blk & 7) * 128 + (blk >> 3);
    const int batch = swz >> 6;
    const int h = swz & 63;

    f32x4 acc[2][4];
#pragma unroll
    for (int mt = 0; mt < 2; ++mt)
#pragma unroll
        for (int nt = 0; nt < 4; ++nt)
            acc[mt][nt] = (f32x4){0.f, 0.f, 0.f, 0.f};

    const int sx = tid & 63;       // x for X staging
    const int sig = tid >> 6;      // ci-octet 0..3

#pragma unroll
    for (int kh = 0; kh < 3; ++kh) {
        const int y = h + kh - 1;
        const bool yok = (y >= 0) && (y < 64);
        for (int kc = 0; kc < 4; ++kc) {
            const int ci0 = kc * 32;
            __syncthreads();       // WAR: prior compute must finish before restage

            // ---- stage X: rows 1..64 <- x 0..63, rows 0 & 65 zero halo ----
            {
                float v[8];
                if (yok) {
                    const float* xp = X + (((size_t)(batch * 128 + ci0 + sig * 8)) * 64 + y) * 64 + sx;
#pragma unroll
                    for (int j = 0; j < 8; ++j) v[j] = xp[(size_t)j * 4096];
                } else {
#pragma unroll
                    for (int j = 0; j < 8; ++j) v[j] = 0.f;
                }
                us8 ph, pl;
#pragma unroll
                for (int j = 0; j < 8; ++j) {
                    unsigned short hb = f2bf(v[j]);
                    ph[j] = hb;
                    pl[j] = f2bf(v[j] - bf2f(hb));
                }
                *(us8*)&sXhi[(sx + 1) * XLD + sig * 8] = ph;
                *(us8*)&sXlo[(sx + 1) * XLD + sig * 8] = pl;
                if (tid < 16) {    // zero halo rows 0 and 65 (32 shorts each, both arrays)
                    int r = (tid & 8) ? 65 : 0;
                    int c = (tid & 3) * 8;
                    unsigned short* dst = (tid & 4) ? sXlo : sXhi;
                    us8 z = {};
                    *(us8*)&dst[r * XLD + c] = z;
                }
            }

            // ---- stage W ----
            if constexpr (PRE) {
#pragma unroll
                for (int rr = 0; rr < 3; ++rr) {
                    int r = tid + rr * 256;            // 0..767 = (kw*2+arr)*128 + co
                    int co = r & 127;
                    int kwa = r >> 7;                  // 0..5
                    int kw = kwa >> 1, arr = kwa & 1;
                    const unsigned short* src =
                        (arr ? wlo : whi) + ((size_t)((batch * 9 + kh * 3 + kw) * 128 + co)) * 128 + ci0;
                    unsigned short* dst = (arr ? sWlo : sWhi) + co * WLD + kw * 32;
                    *(us8*)&dst[0] = *(const us8*)&src[0];
                    *(us8*)&dst[8] = *(const us8*)&src[8];
                    *(us8*)&dst[16] = *(const us8*)&src[16];
                    *(us8*)&dst[24] = *(const us8*)&src[24];
                }
            } else {
                // gather fallback: W[b][co][ci0+i][kh][kw], stride-9 scalar loads
                int co = tid >> 1;
                int i0 = (tid & 1) * 16;
                const float* wp = Wg + ((size_t)(batch * 128 + co) * 128 + ci0 + i0) * 9 + kh * 3;
#pragma unroll
                for (int i = 0; i < 16; ++i) {
#pragma unroll
                    for (int kw = 0; kw < 3; ++kw) {
                        float v = wp[i * 9 + kw];
                        unsigned short hb = f2bf(v);
                        sWhi[co * WLD + kw * 32 + i0 + i] = hb;
                        sWlo[co * WLD + kw * 32 + i0 + i] = f2bf(v - bf2f(hb));
                    }
                }
            }
            __syncthreads();

            // ---- compute: 3 kw steps, K=32 each ----
#pragma unroll
            for (int kw = 0; kw < 3; ++kw) {
                bf16x8 ah[2], al[2], bh[4], bl[4];
#pragma unroll
                for (int mt = 0; mt < 2; ++mt) {
                    int off = (wv * 32 + mt * 16 + l15) * WLD + kw * 32 + lg * 8;
                    ah[mt] = *(const bf16x8*)&sWhi[off];
                    al[mt] = *(const bf16x8*)&sWlo[off];
                }
#pragma unroll
                for (int nt = 0; nt < 4; ++nt) {
                    int off = (nt * 16 + l15 + kw) * XLD + lg * 8;
                    bh[nt] = *(const bf16x8*)&sXhi[off];
                    bl[nt] = *(const bf16x8*)&sXlo[off];
                }
#pragma unroll
                for (int mt = 0; mt < 2; ++mt)
#pragma unroll
                    for (int nt = 0; nt < 4; ++nt) {
                        acc[mt][nt] = MFMA16(ah[mt], bh[nt], acc[mt][nt], 0, 0, 0);
                        acc[mt][nt] = MFMA16(ah[mt], bl[nt], acc[mt][nt], 0, 0, 0);
                        acc[mt][nt] = MFMA16(al[mt], bh[nt], acc[mt][nt], 0, 0, 0);
                    }
            }
        }
    }

    // ---- epilogue: residual add, fp32 out ----
#pragma unroll
    for (int mt = 0; mt < 2; ++mt) {
#pragma unroll
        for (int j = 0; j < 4; ++j) {
            int co = wv * 32 + mt * 16 + lg * 4 + j;
            size_t base = ((size_t)(batch * 128 + co) * 64 + h) * 64;
#pragma unroll
            for (int nt = 0; nt < 4; ++nt) {
                int px = nt * 16 + l15;
                out[base + px] = X[base + px] + acc[mt][nt][j];
            }
        }
    }
}

extern "C" void kernel_launch(void* const* d_in, const int* in_sizes, int n_in,
                              void* d_out, int out_size, void* d_ws, size_t ws_size,
                              hipStream_t stream) {
    const float* inp = (const float*)d_in[0];
    const float* wgt = (const float*)d_in[1];
    float* out = (float*)d_out;

    const size_t welems = (size_t)16 * 9 * 128 * 128;   // 2,359,296 per array
    const size_t wneed = welems * 2 * 2;                // hi+lo, 2B each = 9.44 MB

    if (ws_size >= wneed) {
        unsigned short* whi = (unsigned short*)d_ws;
        unsigned short* wlo = whi + welems;
        w_prepass<<<1152, 256, 0, stream>>>(wgt, whi, wlo);
        conv_main<true><<<1024, 256, 0, stream>>>(inp, wgt, whi, wlo, out);
    } else {
        conv_main<false><<<1024, 256, 0, stream>>>(inp, wgt, nullptr, nullptr, out);
    }
}

// Round 3
// 113.528 us; speedup vs baseline: 1.5969x; 1.5969x over previous
//
#include <hip/hip_runtime.h>
#include <hip/hip_bf16.h>

// out[b,co,h,w] = in[b,co,h,w] + sum_{ci,kh,kw} in[b,ci,h+kh-1,w+kw-1] * W[b,co,ci,kh,kw]
// B=16, C=128, H=W=64, K=3, pad=1, fp32 in/out.
// Single-term fp16 implicit GEMM on mfma_f32_32x32x16_f16 (fp16 RNE err ~5e-3 absmax;
// the bf16-split scheme already passed at 0.03125, so fp16 has 6x margin).

typedef _Float16 h8 __attribute__((ext_vector_type(8)));
typedef _Float16 h4 __attribute__((ext_vector_type(4)));
typedef float f32x16 __attribute__((ext_vector_type(16)));
typedef float f4 __attribute__((ext_vector_type(4)));

#define MFMA32 __builtin_amdgcn_mfma_f32_32x32x16_f16

// ---------------- W prepass: W[b][co][ci][kh][kw] fp32 -> wp[b][kh][kc][kwoct12][co128][ci8] fp16 ----
// Coalesced read -> padded-LDS transpose -> 128B-segment coalesced writes.
// Block = (b, co-group of 8): reads 8*128*9 = 9216 contiguous floats.
__global__ __launch_bounds__(256) void w_prepass(const float* __restrict__ W,
                                                 _Float16* __restrict__ wp) {
    __shared__ float raw[8 * 1153];       // 8 co rows of 1152, +1 pad (bank-conflict-free transpose)
    const int bid = blockIdx.x;           // 256 = b16 * cog16
    const int b   = bid >> 4;
    const int co0 = (bid & 15) * 8;
    const int t   = threadIdx.x;

    const float* src = W + (size_t)(b * 128 + co0) * 1152;
#pragma unroll
    for (int i = 0; i < 9; ++i) {         // 2304 f4 chunks; rows are 1152 floats (mult of 4, no straddle)
        int idx  = (i * 256 + t) * 4;
        f4 v     = *(const f4*)(src + idx);
        int co_l = idx / 1152;
        int rem  = idx - co_l * 1152;
        *(f4*)&raw[co_l * 1153 + rem] = v;
    }
    __syncthreads();

#pragma unroll
    for (int i = 0; i < 9; ++i) {         // 2304 h4 output chunks
        int c    = i * 256 + t;
        int jh   = c & 1;
        int co_l = (c >> 1) & 7;
        int oct  = (c >> 4) & 3;
        int r    = c >> 6;                // 0..35 = (kh*4+kc)*3 + kw
        int kw   = r % 3;
        int r2   = r / 3;
        int kc   = r2 & 3;
        int kh   = r2 >> 2;
        int cib  = kc * 32 + oct * 8 + jh * 4;
        h4 v;
#pragma unroll
        for (int jj = 0; jj < 4; ++jj)
            v[jj] = (_Float16)raw[co_l * 1153 + (cib + jj) * 9 + kh * 3 + kw];
        size_t o = ((size_t)(b * 3 + kh) * 4 + kc) * 12288 +
                   (size_t)(kw * 4 + oct) * 1024 + (size_t)(co0 + co_l) * 8 + jh * 4;
        *(h4*)&wp[o] = v;
    }
}

// ---------------- main kernel ----------------
// grid 512 = 16 batches * 32 row-pair tiles; 256 thr = 4 waves.
// Block: batch, out rows {h0, h0+1}, all 128 co, 64 px each row.
// Wave wv: co-half wvM = wv>>1 (64 co), row wr = wv&1. Wave tile 64co x 64px,
// 2x2 32x32 MFMA tiles, acc = 64 VGPR.
// LDS: sX[2y][4oct][66x'][8ci] fp16 (halo x'=0,65 zeroed once), sW[12kwoct][128co][8ci] fp16.
// 12 stages (kh3 x kc4), K=96 per stage. T14: issue stage s+1 global loads before compute(s).

__global__ __launch_bounds__(256, 2) void conv_main(const float* __restrict__ X,
                                                    const _Float16* __restrict__ wp,
                                                    float* __restrict__ out) {
    __shared__ _Float16 sX[2 * 4 * 66 * 8];    // 8448 B
    __shared__ _Float16 sW[12 * 128 * 8];      // 24576 B

    const int t    = threadIdx.x;
    const int lane = t & 63;
    const int l31  = lane & 31;
    const int lhi  = lane >> 5;
    const int wv   = t >> 6;
    const int wvM  = wv >> 1;
    const int wr   = wv & 1;

    const int bid   = blockIdx.x;
    const int batch = bid >> 5;
    const int h0    = (bid & 31) * 2;

    // staging map: thread -> (y row, 4 x-positions, 4 ci)
    const int sy  = t >> 7;            // 0..1
    const int xq  = (t & 15) * 4;      // x base
    const int cio = (t >> 4) & 7;      // ci quad index (ci_local = cio*4 + j)

    f32x16 acc[2][2];
#pragma unroll
    for (int mt = 0; mt < 2; ++mt)
#pragma unroll
        for (int nt = 0; nt < 2; ++nt)
#pragma unroll
            for (int r = 0; r < 16; ++r) acc[mt][nt][r] = 0.f;

    // zero halo slots x'=0 and x'=65 (written once, never overwritten by staging)
    if (t < 16) {
        int y = t >> 3, oct = (t >> 1) & 3, xp = (t & 1) * 65;
        h8 z;
#pragma unroll
        for (int j = 0; j < 8; ++j) z[j] = (_Float16)0.f;
        *(h8*)&sX[((y * 4 + oct) * 66 + xp) * 8] = z;
    }

    f4 xrv[4];     // X stage regs: 4 ci x 4 x (fp32)
    h8 wreg[6];    // W stage regs: 96 B

    auto load_stage = [&](int s) {
        const int kh = s >> 2, kc = s & 3;
        const int yy = h0 + sy + kh - 1;
        if (yy >= 0 && yy < 64) {
            const float* xp = X + ((size_t)(batch * 128 + kc * 32 + cio * 4) * 64 + yy) * 64 + xq;
#pragma unroll
            for (int j = 0; j < 4; ++j) xrv[j] = *(const f4*)(xp + (size_t)j * 4096);
        } else {
#pragma unroll
            for (int j = 0; j < 4; ++j) xrv[j] = (f4){0.f, 0.f, 0.f, 0.f};
        }
        const _Float16* wsrc = wp + ((size_t)(batch * 3 + kh) * 4 + kc) * 12288 + t * 8;
#pragma unroll
        for (int r = 0; r < 6; ++r) wreg[r] = *(const h8*)(wsrc + (size_t)r * 2048);
    };
    auto write_stage = [&]() {
#pragma unroll
        for (int k = 0; k < 4; ++k) {   // x positions
            h4 v = {(_Float16)xrv[0][k], (_Float16)xrv[1][k],
                    (_Float16)xrv[2][k], (_Float16)xrv[3][k]};
            *(h4*)&sX[((sy * 4 + (cio >> 1)) * 66 + xq + 1 + k) * 8 + (cio & 1) * 4] = v;
        }
#pragma unroll
        for (int r = 0; r < 6; ++r) *(h8*)&sW[(r * 256 + t) * 8] = wreg[r];
    };

    // ---- prologue ----
    load_stage(0);
    __syncthreads();          // halo zero writes visible before any compute
    write_stage();
    __syncthreads();

    // ---- main loop: 12 stages ----
#pragma unroll 1
    for (int s = 0; s < 12; ++s) {
        if (s < 11) load_stage(s + 1);   // global loads in flight during compute(s)

#pragma unroll
        for (int ks = 0; ks < 6; ++ks) {
            const int kw = ks >> 1, kk = ks & 1;
            h8 af[2], bf[2];
#pragma unroll
            for (int mt = 0; mt < 2; ++mt)
                af[mt] = *(const h8*)&sW[((kw * 4 + kk * 2 + lhi) * 128 + wvM * 64 + mt * 32 + l31) * 8];
#pragma unroll
            for (int nt = 0; nt < 2; ++nt)
                bf[nt] = *(const h8*)&sX[((wr * 4 + kk * 2 + lhi) * 66 + nt * 32 + l31 + kw) * 8];
#pragma unroll
            for (int mt = 0; mt < 2; ++mt)
#pragma unroll
                for (int nt = 0; nt < 2; ++nt)
                    acc[mt][nt] = MFMA32(af[mt], bf[nt], acc[mt][nt], 0, 0, 0);
        }

        if (s < 11) {
            __syncthreads();     // all waves done reading stage s
            write_stage();       // compiler inserts vmcnt wait on xrv/wreg
            __syncthreads();     // stage s+1 ready
        }
    }

    // ---- epilogue: residual add + store ----
#pragma unroll
    for (int mt = 0; mt < 2; ++mt)
#pragma unroll
        for (int nt = 0; nt < 2; ++nt)
#pragma unroll
            for (int rg = 0; rg < 16; ++rg) {
                int co = wvM * 64 + mt * 32 + (rg & 3) + 8 * (rg >> 2) + 4 * lhi;
                int x  = nt * 32 + l31;
                size_t o = ((size_t)(batch * 128 + co) * 64 + h0 + wr) * 64 + x;
                out[o] = X[o] + acc[mt][nt][rg];
            }
}

extern "C" void kernel_launch(void* const* d_in, const int* in_sizes, int n_in,
                              void* d_out, int out_size, void* d_ws, size_t ws_size,
                              hipStream_t stream) {
    const float* inp = (const float*)d_in[0];
    const float* wgt = (const float*)d_in[1];
    float* out = (float*)d_out;
    _Float16* wpk = (_Float16*)d_ws;    // 16*3*4*12288 fp16 = 4.72 MB (ws proven >= 9.4 MB in R1)

    w_prepass<<<256, 256, 0, stream>>>(wgt, wpk);
    conv_main<<<512, 256, 0, stream>>>(inp, wpk, out);
}

// Round 6
// 111.836 us; speedup vs baseline: 1.6211x; 1.0151x over previous
//
#include <hip/hip_runtime.h>
#include <hip/hip_bf16.h>

// out[b,co,h,w] = in[b,co,h,w] + sum_{ci,kh,kw} in[b,ci,h+kh-1,w+kw-1] * W[b,co,ci,kh,kw]
// B=16, C=128, H=W=64, K=3, pad=1, fp32 in/out.
// fp16 implicit GEMM on mfma_f32_32x32x16_f16. R4: single-barrier double-buffered
// pipeline + global_load_lds for W + XCD swizzle.

typedef _Float16 h8 __attribute__((ext_vector_type(8)));
typedef _Float16 h4 __attribute__((ext_vector_type(4)));
typedef float f32x16 __attribute__((ext_vector_type(16)));
typedef float f4 __attribute__((ext_vector_type(4)));

#define MFMA32 __builtin_amdgcn_mfma_f32_32x32x16_f16

// async 16B global->LDS. Per-lane lds addr = uniform_base + lane*16 here, which matches
// the HW contract (readfirstlane(base) + lane*16), and also makes the fallback correct.
__device__ __forceinline__ void lds_load16(const void* g, void* l) {
#if __has_builtin(__builtin_amdgcn_global_load_lds)
    __builtin_amdgcn_global_load_lds((__attribute__((address_space(1))) const void*)g,
                                     (__attribute__((address_space(3))) void*)l, 16, 0, 0);
#else
    *(f4*)l = *(const f4*)g;
#endif
}

// ---------------- W prepass: W[b][co][ci][kh][kw] fp32 -> wp[b][kh][kc][kwoct12][co128][ci8] fp16 ----
__global__ __launch_bounds__(256) void w_prepass(const float* __restrict__ W,
                                                 _Float16* __restrict__ wp) {
    __shared__ float raw[8 * 1153];
    const int bid = blockIdx.x;           // 256 = b16 * cog16
    const int b   = bid >> 4;
    const int co0 = (bid & 15) * 8;
    const int t   = threadIdx.x;

    const float* src = W + (size_t)(b * 128 + co0) * 1152;
#pragma unroll
    for (int i = 0; i < 9; ++i) {
        int idx  = (i * 256 + t) * 4;
        f4 v     = *(const f4*)(src + idx);
        int co_l = idx / 1152;
        int rem  = idx - co_l * 1152;
        *(f4*)&raw[co_l * 1153 + rem] = v;
    }
    __syncthreads();

#pragma unroll
    for (int i = 0; i < 9; ++i) {
        int c    = i * 256 + t;
        int jh   = c & 1;
        int co_l = (c >> 1) & 7;
        int oct  = (c >> 4) & 3;
        int r    = c >> 6;                // 0..35 = (kh*4+kc)*3 + kw
        int kw   = r % 3;
        int r2   = r / 3;
        int kc   = r2 & 3;
        int kh   = r2 >> 2;
        int cib  = kc * 32 + oct * 8 + jh * 4;
        h4 v;
#pragma unroll
        for (int jj = 0; jj < 4; ++jj)
            v[jj] = (_Float16)raw[co_l * 1153 + (cib + jj) * 9 + kh * 3 + kw];
        size_t o = ((size_t)(b * 3 + kh) * 4 + kc) * 12288 +
                   (size_t)(kw * 4 + oct) * 1024 + (size_t)(co0 + co_l) * 8 + jh * 4;
        *(h4*)&wp[o] = v;
    }
}

// ---------------- main kernel ----------------
// grid 512 = 16 b * 32 row-pairs (XCD-swizzled); 256 thr = 4 waves.
// Wave wv: co-half wvM=wv>>1, row wr=wv&1; wave tile 64co x 64px, 2x2 32x32 MFMA, acc 64 VGPR.
// LDS (double-buffered): sX[2][2y][4oct][66x'][8ci], sW[2][12 kwoct][128co][8ci]. 66 KB total.
// 12 stages (kh3 x kc4), K=96/stage, ONE barrier per stage.

__global__ __launch_bounds__(256, 2) void conv_main(const float* __restrict__ X,
                                                    const _Float16* __restrict__ wp,
                                                    float* __restrict__ out) {
    __shared__ _Float16 sX[2 * 4224];     // 2*2*4*66*8
    __shared__ _Float16 sW[2 * 12288];    // 2*12*128*8

    const int t    = threadIdx.x;
    const int lane = t & 63;
    const int l31  = lane & 31;
    const int lhi  = lane >> 5;
    const int wv   = t >> 6;
    const int wvM  = wv >> 1;
    const int wr   = wv & 1;

    // XCD swizzle: blocks bid%8==k -> swz in [k*64,(k+1)*64) -> batches {2k,2k+1}
    const int bid   = blockIdx.x;
    const int swz   = (bid & 7) * 64 + (bid >> 3);
    const int batch = swz >> 5;
    const int h0    = (swz & 31) * 2;

    const int sy  = t >> 7;            // staging: y row 0..1
    const int xq  = (t & 15) * 4;      // 4 x-positions
    const int cio = (t >> 4) & 7;      // ci quad (ci_local = cio*4 + j)

    f32x16 acc[2][2];
#pragma unroll
    for (int mt = 0; mt < 2; ++mt)
#pragma unroll
        for (int nt = 0; nt < 2; ++nt)
#pragma unroll
            for (int r = 0; r < 16; ++r) acc[mt][nt][r] = 0.f;

    // zero halo slots (x'=0,65) in BOTH buffers, once
    if (t < 32) {
        int pb = t >> 4, y = (t >> 3) & 1, oct = (t >> 1) & 3, side = t & 1;
        h8 z = {};
        *(h8*)&sX[pb * 4224 + ((y * 4 + oct) * 66 + side * 65) * 8] = z;
    }

    f4 xrv[4];

    auto issue_stage = [&](int s, int pb) {
        const int kh = s >> 2, kc = s & 3;
        // W: async global->LDS (already fp16, slab is linear)
        const _Float16* wsrc = wp + ((size_t)(batch * 3 + kh) * 4 + kc) * 12288 + (size_t)t * 8;
        _Float16* wdst = sW + pb * 12288 + t * 8;
#pragma unroll
        for (int r = 0; r < 6; ++r)
            lds_load16(wsrc + (size_t)r * 2048, wdst + r * 2048);
        // X: reg load (fp32 -> needs cvt)
        const int yy = h0 + sy + kh - 1;
        if (yy >= 0 && yy < 64) {
            const float* xp = X + ((size_t)(batch * 128 + kc * 32 + cio * 4) * 64 + yy) * 64 + xq;
#pragma unroll
            for (int j = 0; j < 4; ++j) xrv[j] = *(const f4*)(xp + (size_t)j * 4096);
        } else {
#pragma unroll
            for (int j = 0; j < 4; ++j) xrv[j] = (f4){0.f, 0.f, 0.f, 0.f};
        }
    };

    auto write_x = [&](int pb) {
#pragma unroll
        for (int k = 0; k < 4; ++k) {
            h4 v = {(_Float16)xrv[0][k], (_Float16)xrv[1][k],
                    (_Float16)xrv[2][k], (_Float16)xrv[3][k]};
            *(h4*)&sX[pb * 4224 + ((sy * 4 + (cio >> 1)) * 66 + xq + 1 + k) * 8 + (cio & 1) * 4] = v;
        }
    };

    auto compute = [&](int pb) {
        const _Float16* sWp = sW + pb * 12288;
        const _Float16* sXp = sX + pb * 4224;
#pragma unroll
        for (int ks = 0; ks < 6; ++ks) {
            const int kw = ks >> 1, kk = ks & 1;
            h8 af[2], bf[2];
#pragma unroll
            for (int mt = 0; mt < 2; ++mt)
                af[mt] = *(const h8*)&sWp[((kw * 4 + kk * 2 + lhi) * 128 + wvM * 64 + mt * 32 + l31) * 8];
#pragma unroll
            for (int nt = 0; nt < 2; ++nt)
                bf[nt] = *(const h8*)&sXp[((wr * 4 + kk * 2 + lhi) * 66 + nt * 32 + l31 + kw) * 8];
#pragma unroll
            for (int mt = 0; mt < 2; ++mt)
#pragma unroll
                for (int nt = 0; nt < 2; ++nt)
                    acc[mt][nt] = MFMA32(af[mt], bf[nt], acc[mt][nt], 0, 0, 0);
        }
    };

    // ---- prologue ----
    issue_stage(0, 0);
    write_x(0);                                        // waits vmcnt for xrv
    asm volatile("s_waitcnt vmcnt(0)" ::: "memory");   // W DMA landed
    __syncthreads();

    // ---- main loop: one barrier per stage ----
    int p = 0;
#pragma unroll 1
    for (int s = 0; s < 11; ++s) {
        issue_stage(s + 1, p ^ 1);   // global loads in flight during compute(s)
        compute(p);
        write_x(p ^ 1);
        asm volatile("s_waitcnt vmcnt(0)" ::: "memory");
        __syncthreads();
        p ^= 1;
    }
    compute(p);

    // ---- epilogue: residual add + store ----
#pragma unroll
    for (int mt = 0; mt < 2; ++mt)
#pragma unroll
        for (int nt = 0; nt < 2; ++nt)
#pragma unroll
            for (int rg = 0; rg < 16; ++rg) {
                int co = wvM * 64 + mt * 32 + (rg & 3) + 8 * (rg >> 2) + 4 * lhi;
                int x  = nt * 32 + l31;
                size_t o = ((size_t)(batch * 128 + co) * 64 + h0 + wr) * 64 + x;
                out[o] = X[o] + acc[mt][nt][rg];
            }
}

extern "C" void kernel_launch(void* const* d_in, const int* in_sizes, int n_in,
                              void* d_out, int out_size, void* d_ws, size_t ws_size,
                              hipStream_t stream) {
    const float* inp = (const float*)d_in[0];
    const float* wgt = (const float*)d_in[1];
    float* out = (float*)d_out;
    _Float16* wpk = (_Float16*)d_ws;    // 16*3*4*12288 fp16 = 4.72 MB

    w_prepass<<<256, 256, 0, stream>>>(wgt, wpk);
    conv_main<<<512, 256, 0, stream>>>(inp, wpk, out);
}